// Round 8
// baseline (286.743 us; speedup 1.0000x reference)
//
#include <hip/hip_runtime.h>
#include <hip/hip_bf16.h>
#include <stdint.h>

#define NN 16384
#define BM 32
#define BK 64
#define NSTEPS (NN / BK)   // 256

typedef __attribute__((ext_vector_type(8))) short bf16x8;   // MFMA A/B frag: 8 bf16
typedef __attribute__((ext_vector_type(4))) float f32x4;
typedef __attribute__((ext_vector_type(4))) unsigned short u16x4;
typedef __attribute__((ext_vector_type(8))) unsigned short u16x8;
typedef __attribute__((ext_vector_type(4))) unsigned int u32x4;

__device__ __forceinline__ unsigned short f2bf(float f) {
    uint32_t u = __builtin_bit_cast(uint32_t, f);
    u += 0x7fffu + ((u >> 16) & 1u);   // RNE; inputs are finite
    return (unsigned short)(u >> 16);
}

// Tiled transpose: neighT[c][r] = bf16(neigh[r][c]). Coalesced reads AND writes.
__global__ __launch_bounds__(256) void prep_transpose(const float* __restrict__ src,
                                                      unsigned short* __restrict__ dstT) {
    __shared__ unsigned short tl[128][66];   // [c][r], pad to break bank alias
    const int t = threadIdx.x;
    const int r0 = blockIdx.x * 64;
#pragma unroll
    for (int i = 0; i < 8; ++i) {
        int idx = i * 256 + t;
        int r = idx >> 5;            // 0..63
        int s = idx & 31;            // f32x4 slot within 128-col row
        f32x4 v = *(const f32x4*)(src + (size_t)(r0 + r) * 128 + s * 4);
#pragma unroll
        for (int j = 0; j < 4; ++j) tl[s * 4 + j][r] = f2bf(v[j]);
    }
    __syncthreads();
    const int c = t >> 1;
    const int half = t & 1;
#pragma unroll
    for (int j = 0; j < 4; ++j) {
        u16x8 p;
#pragma unroll
        for (int e = 0; e < 8; ++e) p[e] = tl[c][half * 32 + j * 8 + e];
        *(u16x8*)(dstT + (size_t)c * NN + r0 + half * 32 + j * 8) = p;
    }
}

#define MFMA16(a, b, c) __builtin_amdgcn_mfma_f32_16x16x32_bf16(a, b, c, 0, 0, 0)

// Raw barrier: make ds_writes visible (lgkmcnt only), do NOT drain vmcnt.
// Single trailing sched_barrier keeps later LDS reads from hoisting above s_barrier.
#define BARRIER() do {                                          \
    asm volatile("s_waitcnt lgkmcnt(0)" ::: "memory");          \
    __builtin_amdgcn_s_barrier();                               \
    __builtin_amdgcn_sched_barrier(0);                          \
} while (0)

__global__ __launch_bounds__(256, 2) void sage_fused(
    const float* __restrict__ adj,
    const float* __restrict__ feat,
    const unsigned short* __restrict__ neighT,
    const float* __restrict__ W,
    float* __restrict__ out)
{
    // LDS 40.1 KB (a 8K + b 32K; epilogue d_lds 16K aliases the front; degp tail)
    __shared__ __align__(16) char smem[41088];
    char* aL = smem;                        // [2][BM*BK] bf16, swizzled
    char* bL = smem + 8192;                 // [2][128*BK] bf16, swizzled
    char* dL = smem;                        // epilogue [BM*256] bf16, swizzled (alias)
    float* degp = (float*)(smem + 40960);   // [BM]

    const int t = threadIdx.x;
    const int lane = t & 63;
    const int wv = t >> 6;        // wave 0..3
    const int mt = wv >> 1;       // wave row 0..1 (16 rows each)
    const int nt = wv & 1;        // wave col 0..1 (64 cols each)
    const size_t row0 = (size_t)blockIdx.x * BM;

    if (t < BM) degp[t] = 0.f;

    // A (f32): i=0..1: row = 16*i + (t>>4), float4-slot = t&15
    const int ar0 = t >> 4;
    const int acs = (t & 15) * 4;
    // B (bf16): i=0..3: row(c) = 32*i + (t>>3), 16B-slot = t&7
    const int br0 = t >> 3;
    const int bcs = (t & 7) * 8;

    const float* aG = adj + (row0 + ar0) * (size_t)NN + acs;
    const unsigned short* bG = neighT + (size_t)br0 * NN + bcs;

    int awb[2], bwb[4];
#pragma unroll
    for (int i = 0; i < 2; ++i) {
        int ar = ar0 + 16 * i;
        awb[i] = ((ar * (BK * 2)) + acs * 2) ^ ((ar & 7) << 4);
    }
#pragma unroll
    for (int i = 0; i < 4; ++i) {
        int br = br0 + 32 * i;
        bwb[i] = ((br * (BK * 2)) + bcs * 2) ^ ((br & 7) << 4);
    }

    f32x4 acc[4];
#pragma unroll
    for (int j = 0; j < 4; ++j) acc[j] = (f32x4){0.f, 0.f, 0.f, 0.f};

    float dsum[2] = {0.f, 0.f};

    f32x4 arA[2], arB[2];
    u32x4 brA[4], brB[4];

#define ISSUE(AR, BR, KOFF) do {                                              \
    _Pragma("unroll")                                                         \
    for (int i = 0; i < 2; ++i)                                               \
        AR[i] = __builtin_nontemporal_load(                                   \
            (const f32x4*)(aG + (size_t)(16 * i) * NN + (KOFF)));             \
    _Pragma("unroll")                                                         \
    for (int i = 0; i < 4; ++i)                                               \
        BR[i] = *(const u32x4*)(bG + (size_t)(32 * i) * NN + (KOFF));         \
} while (0)

#define STAGE(AR, BR, BUF) do {                                               \
    char* aW = aL + (BUF) * (BM * BK * 2);                                    \
    char* bW = bL + (BUF) * (128 * BK * 2);                                   \
    _Pragma("unroll")                                                         \
    for (int i = 0; i < 2; ++i) {                                             \
        f32x4 v = AR[i];                                                      \
        dsum[i] += (v[0] + v[1]) + (v[2] + v[3]);                             \
        u16x4 p; p.x = f2bf(v[0]); p.y = f2bf(v[1]);                          \
        p.z = f2bf(v[2]); p.w = f2bf(v[3]);                                   \
        *(u16x4*)(aW + awb[i]) = p;                                           \
    }                                                                         \
    _Pragma("unroll")                                                         \
    for (int i = 0; i < 4; ++i)                                               \
        *(u32x4*)(bW + bwb[i]) = BR[i];                                       \
} while (0)

#define COMPUTE(BUF) do {                                                     \
    const char* aB = aL + (BUF) * (BM * BK * 2);                              \
    const char* bB = bL + (BUF) * (128 * BK * 2);                             \
    _Pragma("unroll")                                                         \
    for (int ks = 0; ks < 2; ++ks) {                                          \
        bf16x8 af, bfr[4];                                                    \
        {                                                                     \
            int r = mt * 16 + (lane & 15);                                    \
            int off = (r * (BK * 2) + ks * 64 + (lane >> 4) * 16)             \
                      ^ ((r & 7) << 4);                                       \
            af = *(const bf16x8*)(aB + off);                                  \
        }                                                                     \
        _Pragma("unroll")                                                     \
        for (int ns = 0; ns < 4; ++ns) {                                      \
            int c = nt * 64 + ns * 16 + (lane & 15);                          \
            int off = (c * (BK * 2) + ks * 64 + (lane >> 4) * 16)             \
                      ^ ((c & 7) << 4);                                       \
            bfr[ns] = *(const bf16x8*)(bB + off);                             \
        }                                                                     \
        _Pragma("unroll")                                                     \
        for (int ns = 0; ns < 4; ++ns)                                        \
            acc[ns] = MFMA16(af, bfr[ns], acc[ns]);                           \
    }                                                                         \
} while (0)

    // prologue: stage tile 0 (one-time full-latency stall); tile 1 left in flight
    ISSUE(arA, brA, 0);
    STAGE(arA, brA, 0);
    ISSUE(arB, brB, BK);
    BARRIER();

    // steady state (depth-2): at even top, buf0 = tile kt staged;
    // in flight: tile kt+1 (arB/brB). STAGE's dependency-wait is vmcnt(6):
    // it waits only for loads issued a FULL interval earlier; the 6 loads of
    // tile kt+2 remain outstanding across the barrier -> sustained HBM demand.
    for (int kt = 0; kt < NSTEPS; kt += 2) {
        if (kt + 2 < NSTEPS) ISSUE(arA, brA, (size_t)(kt + 2) * BK);
        COMPUTE(0);
        STAGE(arB, brB, 1);                 // tile kt+1 (always < NSTEPS)
        BARRIER();

        if (kt + 3 < NSTEPS) ISSUE(arB, brB, (size_t)(kt + 3) * BK);
        COMPUTE(1);
        if (kt + 2 < NSTEPS) STAGE(arA, brA, 0);
        BARRIER();
    }

    // ---- degree reduction ----
#pragma unroll
    for (int i = 0; i < 2; ++i)
        atomicAdd(&degp[ar0 + 16 * i], dsum[i]);
    __syncthreads();   // full drain; also fences before d_lds aliases the main buffers

    // ---- h = S/deg -> d_lds cols [128,256) ----
#pragma unroll
    for (int ns = 0; ns < 4; ++ns)
#pragma unroll
        for (int j = 0; j < 4; ++j) {
            int r = mt * 16 + (lane >> 4) * 4 + j;
            int c = 128 + nt * 64 + ns * 16 + (lane & 15);
            float v = acc[ns][j] / (degp[r] + 1.0f);
            int off = (r * 512 + c * 2) ^ ((r & 7) << 4);
            *(unsigned short*)(dL + off) = f2bf(v);
        }

    // ---- features -> d_lds cols [0,128) ----
#pragma unroll
    for (int i = 0; i < 4; ++i) {
        int idx = i * 256 + t;
        int r = idx >> 5;          // 32 float4-slots per 128-f32 row
        int s = idx & 31;
        f32x4 v = *(const f32x4*)(feat + (row0 + r) * 128 + s * 4);
        u16x4 p; p.x = f2bf(v[0]); p.y = f2bf(v[1]); p.z = f2bf(v[2]); p.w = f2bf(v[3]);
        int off = (r * 512 + s * 8) ^ ((r & 7) << 4);
        *(u16x4*)(dL + off) = p;
    }
    __syncthreads();

    // ---- out = data(32x256) @ W^T via MFMA, K=256; W frags straight from global f32 ----
    f32x4 acc2[4];
#pragma unroll
    for (int j = 0; j < 4; ++j) acc2[j] = (f32x4){0.f, 0.f, 0.f, 0.f};

#pragma unroll
    for (int ks = 0; ks < 8; ++ks) {
        bf16x8 af, bfr[4];
        {
            int r = mt * 16 + (lane & 15);
            int off = (r * 512 + ks * 64 + (lane >> 4) * 16) ^ ((r & 7) << 4);
            af = *(const bf16x8*)(dL + off);
        }
#pragma unroll
        for (int ns = 0; ns < 4; ++ns) {
            int c = nt * 64 + ns * 16 + (lane & 15);
            int k0 = ks * 32 + (lane >> 4) * 8;
            f32x4 w0 = *(const f32x4*)(W + (size_t)c * 256 + k0);
            f32x4 w1 = *(const f32x4*)(W + (size_t)c * 256 + k0 + 4);
            u16x8 p;
            p[0] = f2bf(w0[0]); p[1] = f2bf(w0[1]); p[2] = f2bf(w0[2]); p[3] = f2bf(w0[3]);
            p[4] = f2bf(w1[0]); p[5] = f2bf(w1[1]); p[6] = f2bf(w1[2]); p[7] = f2bf(w1[3]);
            bfr[ns] = __builtin_bit_cast(bf16x8, p);
        }
#pragma unroll
        for (int ns = 0; ns < 4; ++ns)
            acc2[ns] = MFMA16(af, bfr[ns], acc2[ns]);
    }

    // ---- store f32 ----
#pragma unroll
    for (int ns = 0; ns < 4; ++ns)
#pragma unroll
        for (int j = 0; j < 4; ++j) {
            int r = mt * 16 + (lane >> 4) * 4 + j;
            int c = nt * 64 + ns * 16 + (lane & 15);
            out[(row0 + r) * 128 + c] = acc2[ns][j];
        }
}

extern "C" void kernel_launch(void* const* d_in, const int* in_sizes, int n_in,
                              void* d_out, int out_size, void* d_ws, size_t ws_size,
                              hipStream_t stream) {
    const float* adj = (const float*)d_in[0];
    const float* feat = (const float*)d_in[1];
    const float* neigh = (const float*)d_in[2];
    const float* W = (const float*)d_in[3];
    float* out = (float*)d_out;
    unsigned short* neighT = (unsigned short*)d_ws;   // 128 x 16384 bf16 = 4 MiB

    prep_transpose<<<NN / 64, 256, 0, stream>>>(neigh, neighT);
    sage_fused<<<NN / BM, 256, 0, stream>>>(adj, feat, neighT, W, out);
}

// Round 9
// 250.503 us; speedup vs baseline: 1.1447x; 1.1447x over previous
//
#include <hip/hip_runtime.h>
#include <hip/hip_bf16.h>
#include <stdint.h>

#define NN 16384
#define BM 32
#define BKA 256              // A staged k-depth: 1 KB per row per burst
#define BKB 64               // compute / B substep k-depth
#define NGROUPS (NN / BKA)   // 64
#define NKT (NN / BKB)       // 256

typedef __attribute__((ext_vector_type(8))) short bf16x8;   // MFMA A/B frag
typedef __attribute__((ext_vector_type(4))) float f32x4;
typedef __attribute__((ext_vector_type(4))) unsigned short u16x4;
typedef __attribute__((ext_vector_type(8))) unsigned short u16x8;
typedef __attribute__((ext_vector_type(4))) unsigned int u32x4;

__device__ __forceinline__ unsigned short f2bf(float f) {
    uint32_t u = __builtin_bit_cast(uint32_t, f);
    u += 0x7fffu + ((u >> 16) & 1u);   // RNE; inputs are finite
    return (unsigned short)(u >> 16);
}

// Tiled transpose: neighT[c][r] = bf16(neigh[r][c]). Coalesced reads AND writes.
__global__ __launch_bounds__(256) void prep_transpose(const float* __restrict__ src,
                                                      unsigned short* __restrict__ dstT) {
    __shared__ unsigned short tl[128][66];
    const int t = threadIdx.x;
    const int r0 = blockIdx.x * 64;
#pragma unroll
    for (int i = 0; i < 8; ++i) {
        int idx = i * 256 + t;
        int r = idx >> 5;
        int s = idx & 31;
        f32x4 v = *(const f32x4*)(src + (size_t)(r0 + r) * 128 + s * 4);
#pragma unroll
        for (int j = 0; j < 4; ++j) tl[s * 4 + j][r] = f2bf(v[j]);
    }
    __syncthreads();
    const int c = t >> 1;
    const int half = t & 1;
#pragma unroll
    for (int j = 0; j < 4; ++j) {
        u16x8 p;
#pragma unroll
        for (int e = 0; e < 8; ++e) p[e] = tl[c][half * 32 + j * 8 + e];
        *(u16x8*)(dstT + (size_t)c * NN + r0 + half * 32 + j * 8) = p;
    }
}

#define MFMA16(a, b, c) __builtin_amdgcn_mfma_f32_16x16x32_bf16(a, b, c, 0, 0, 0)

// Raw barrier: ds_writes visible (lgkmcnt only); global loads stay in flight.
// Trailing sched_barrier: later LDS reads must not hoist above s_barrier.
#define BARRIER() do {                                          \
    asm volatile("s_waitcnt lgkmcnt(0)" ::: "memory");          \
    __builtin_amdgcn_s_barrier();                               \
    __builtin_amdgcn_sched_barrier(0);                          \
} while (0)

__global__ __launch_bounds__(256, 2) void sage_fused(
    const float* __restrict__ adj,
    const float* __restrict__ feat,
    const unsigned short* __restrict__ neighT,
    const float* __restrict__ W,
    float* __restrict__ out)
{
    // LDS 64.1 KB -> 2 blocks/CU.
    //  aL: [2][32 rows][512 B] bf16 swizzled (A, k-depth 256)  = 32 KB
    //  bL: [2][128 rows][128 B] bf16 swizzled (B, k-depth 64)  = 32 KB
    //  dL: epilogue [32][512 B] aliases front 16 KB; degp at tail.
    __shared__ __align__(16) char smem[65664];
    char* aL = smem;
    char* bL = smem + 32768;
    char* dL = smem;
    float* degp = (float*)(smem + 65536);

    const int t = threadIdx.x;
    const int lane = t & 63;
    const int wv = t >> 6;        // wave 0..3
    const int mt = wv >> 1;       // wave row 0..1 (16 rows each)
    const int nt = wv & 1;        // wave col 0..1 (64 cols each)
    const size_t row0 = (size_t)blockIdx.x * BM;

    // ---- A staging plan: thread owns row ra = t>>3; 8 lanes per row.
    // Load i covers f32-cols i*32 + asl*4 .. +4  (8 instrs = 1 KB/row burst).
    const int ra = t >> 3;
    const int asl = t & 7;
    const float* aGa = adj + (row0 + ra) * (size_t)NN + asl * 4;

    int awz[8];
#pragma unroll
    for (int i = 0; i < 8; ++i)
        awz[i] = ra * 512 + ((i * 64 + asl * 8) ^ ((ra & 7) << 4));

    // ---- B staging plan (proven R3/R7 pattern)
    const int br0 = t >> 3;
    const int bcs = (t & 7) * 8;
    const unsigned short* bG = neighT + (size_t)br0 * NN + bcs;
    int bwb[4];
#pragma unroll
    for (int i = 0; i < 4; ++i) {
        int br = br0 + 32 * i;
        bwb[i] = (br * 128 + bcs * 2) ^ ((br & 7) << 4);
    }

    f32x4 acc[4];
#pragma unroll
    for (int j = 0; j < 4; ++j) acc[j] = (f32x4){0.f, 0.f, 0.f, 0.f};

    float dsum = 0.f;

    f32x4 arA[8];
    u32x4 br_[4];

#define ISSUE_A(G) do {                                                       \
    _Pragma("unroll")                                                         \
    for (int i = 0; i < 8; ++i)                                               \
        arA[i] = __builtin_nontemporal_load(                                  \
            (const f32x4*)(aGa + (size_t)(G) * BKA + i * 32));                \
} while (0)

#define ISSUE_B(KT) do {                                                      \
    _Pragma("unroll")                                                         \
    for (int i = 0; i < 4; ++i)                                               \
        br_[i] = *(const u32x4*)(bG + (size_t)(32 * i) * NN +                 \
                                 (size_t)(KT) * BKB);                         \
} while (0)

#define STAGE_A(DST) do {                                                     \
    _Pragma("unroll")                                                         \
    for (int i = 0; i < 8; ++i) {                                             \
        f32x4 v = arA[i];                                                     \
        dsum += (v[0] + v[1]) + (v[2] + v[3]);                                \
        u16x4 p; p.x = f2bf(v[0]); p.y = f2bf(v[1]);                          \
        p.z = f2bf(v[2]); p.w = f2bf(v[3]);                                   \
        *(u16x4*)((DST) + awz[i]) = p;                                        \
    }                                                                         \
} while (0)

#define STAGE_B(BUF) do {                                                     \
    char* bW = bL + (BUF) * 16384;                                            \
    _Pragma("unroll")                                                         \
    for (int i = 0; i < 4; ++i)                                               \
        *(u32x4*)(bW + bwb[i]) = br_[i];                                      \
} while (0)

#define COMPUTE(ABASE, SUB, BBUF) do {                                        \
    const char* aB = (ABASE);                                                 \
    const char* bB = bL + (BBUF) * 16384;                                     \
    _Pragma("unroll")                                                         \
    for (int ks = 0; ks < 2; ++ks) {                                          \
        bf16x8 af, bfr[4];                                                    \
        {                                                                     \
            int r = mt * 16 + (lane & 15);                                    \
            int off = r * 512 + (((SUB) * 128 + ks * 64 + (lane >> 4) * 16)   \
                      ^ ((r & 7) << 4));                                      \
            af = *(const bf16x8*)(aB + off);                                  \
        }                                                                     \
        _Pragma("unroll")                                                     \
        for (int ns = 0; ns < 4; ++ns) {                                      \
            int c = nt * 64 + ns * 16 + (lane & 15);                          \
            int off = c * 128 + ((ks * 64 + (lane >> 4) * 16)                 \
                      ^ ((c & 7) << 4));                                      \
            bfr[ns] = *(const bf16x8*)(bB + off);                             \
        }                                                                     \
        _Pragma("unroll")                                                     \
        for (int ns = 0; ns < 4; ++ns)                                        \
            acc[ns] = MFMA16(af, bfr[ns], acc[ns]);                           \
    }                                                                         \
} while (0)

    // prologue: load + stage A-group 0 and B-substep 0 (one-time latency stall)
    ISSUE_B(0);
    ISSUE_A(0);
    STAGE_B(0);
    STAGE_A(aL);
    BARRIER();

    // steady state: group g = 4 substeps over A-tile g.
    //  s==0: issue A(g+1) (8x1KB-per-row bursts, in flight ~3 substeps)
    //  each s: issue B(kt+1) -> compute(kt) -> stage B(kt+1)
    //  s==3: stage A(g+1) (loads long since arrived; counted vmcnt)
    for (int g = 0; g < NGROUPS; ++g) {
        char* aCur = aL + (g & 1) * 16384;
        char* aNxt = aL + ((g & 1) ^ 1) * 16384;
#pragma unroll
        for (int s = 0; s < 4; ++s) {
            const int kt = g * 4 + s;
            if (kt + 1 < NKT) ISSUE_B(kt + 1);
            if (s == 0 && g + 1 < NGROUPS) ISSUE_A(g + 1);
            COMPUTE(aCur, s, s & 1);
            if (kt + 1 < NKT) STAGE_B((s + 1) & 1);
            if (s == 3 && g + 1 < NGROUPS) STAGE_A(aNxt);
            BARRIER();
        }
    }

    // ---- degree: 8-lane shfl tree (threads 8r..8r+7 share row r) ----
#pragma unroll
    for (int m = 1; m < 8; m <<= 1) dsum += __shfl_xor(dsum, m, 64);
    if (asl == 0) degp[ra] = dsum;
    __syncthreads();   // full drain; also fences before dL aliases aL

    // ---- h = S/deg -> dL cols [128,256) ----
#pragma unroll
    for (int ns = 0; ns < 4; ++ns)
#pragma unroll
        for (int j = 0; j < 4; ++j) {
            int r = mt * 16 + (lane >> 4) * 4 + j;
            int c = 128 + nt * 64 + ns * 16 + (lane & 15);
            float v = acc[ns][j] / (degp[r] + 1.0f);
            int off = (r * 512 + c * 2) ^ ((r & 7) << 4);
            *(unsigned short*)(dL + off) = f2bf(v);
        }

    // ---- features -> dL cols [0,128) ----
#pragma unroll
    for (int i = 0; i < 4; ++i) {
        int idx = i * 256 + t;
        int r = idx >> 5;
        int s = idx & 31;
        f32x4 v = *(const f32x4*)(feat + (row0 + r) * 128 + s * 4);
        u16x4 p; p.x = f2bf(v[0]); p.y = f2bf(v[1]); p.z = f2bf(v[2]); p.w = f2bf(v[3]);
        int off = (r * 512 + s * 8) ^ ((r & 7) << 4);
        *(u16x4*)(dL + off) = p;
    }
    __syncthreads();

    // ---- out = data(32x256) @ W^T via MFMA, K=256; W frags from global f32 ----
    f32x4 acc2[4];
#pragma unroll
    for (int j = 0; j < 4; ++j) acc2[j] = (f32x4){0.f, 0.f, 0.f, 0.f};

#pragma unroll
    for (int ks = 0; ks < 8; ++ks) {
        bf16x8 af, bfr[4];
        {
            int r = mt * 16 + (lane & 15);
            int off = (r * 512 + ks * 64 + (lane >> 4) * 16) ^ ((r & 7) << 4);
            af = *(const bf16x8*)(dL + off);
        }
#pragma unroll
        for (int ns = 0; ns < 4; ++ns) {
            int c = nt * 64 + ns * 16 + (lane & 15);
            int k0 = ks * 32 + (lane >> 4) * 8;
            f32x4 w0 = *(const f32x4*)(W + (size_t)c * 256 + k0);
            f32x4 w1 = *(const f32x4*)(W + (size_t)c * 256 + k0 + 4);
            u16x8 p;
            p[0] = f2bf(w0[0]); p[1] = f2bf(w0[1]); p[2] = f2bf(w0[2]); p[3] = f2bf(w0[3]);
            p[4] = f2bf(w1[0]); p[5] = f2bf(w1[1]); p[6] = f2bf(w1[2]); p[7] = f2bf(w1[3]);
            bfr[ns] = __builtin_bit_cast(bf16x8, p);
        }
#pragma unroll
        for (int ns = 0; ns < 4; ++ns)
            acc2[ns] = MFMA16(af, bfr[ns], acc2[ns]);
    }

    // ---- store f32 ----
#pragma unroll
    for (int ns = 0; ns < 4; ++ns)
#pragma unroll
        for (int j = 0; j < 4; ++j) {
            int r = mt * 16 + (lane >> 4) * 4 + j;
            int c = nt * 64 + ns * 16 + (lane & 15);
            out[(row0 + r) * 128 + c] = acc2[ns][j];
        }
}

extern "C" void kernel_launch(void* const* d_in, const int* in_sizes, int n_in,
                              void* d_out, int out_size, void* d_ws, size_t ws_size,
                              hipStream_t stream) {
    const float* adj = (const float*)d_in[0];
    const float* feat = (const float*)d_in[1];
    const float* neigh = (const float*)d_in[2];
    const float* W = (const float*)d_in[3];
    float* out = (float*)d_out;
    unsigned short* neighT = (unsigned short*)d_ws;   // 128 x 16384 bf16 = 4 MiB

    prep_transpose<<<NN / 64, 256, 0, stream>>>(neigh, neighT);
    sage_fused<<<NN / BM, 256, 0, stream>>>(adj, feat, neighT, W, out);
}